// Round 9
// baseline (13.124 us; speedup 1.0000x reference)
//
#include <hip/hip_runtime.h>
#include <math.h>

// BlockwiseQuantizationOptim: 1024x1024 f32, 64 blocks of 128x128, L=256, T=100.
// Closed-form softmax over uniform levels: e_l = r^|p-l|, r = exp(-100/255).
//   S  = rf*Ak + r1f*Aj
//   W  = rf*yK + r1f*yJ,  yK = k*Ak-Bk, yJ = (k+1)*Aj+Bj
// INTERIOR FAST PATH (32 <= k <= 223, >99% of normal data): r^(k+1), r^(255-k)
// < 4e-6 -> Ak=Aj=1/(1-r), yK=k/(1-r)-Binf, yJ=(k+1)/(1-r)+Binf (no exp2).
// Edge lanes take the exact 2-exp2 formula (R8 code, absmax-verified).
// bin_mass: ONE ds_add_u32 per element packing down-seed (level k, bits 0..15)
// and up-seed (level k+1, bits 16..31) as 8.8 fixed point (half-sums < 2^16;
// u32 is the only native-fast LDS atomic — R2/R4 evidence).
// Phases 2+3 fused in-register: per (col, 8-level chunk) both geometric scans
// from 9 packed reads + two width-32 shfl carry scans, entropy in-register.
// Grid 1024 WG x 256 thr (R9: 4 barrier groups/CU instead of 2, same waves).
// Two-kernel finish — no device-scope fences/atomics in the hot kernel
// (R4/R5 regression).
//
// dep LDS layout (8 cols/WG): idx(c,l) = (l&15)*136 + c*17 + (l>>4)

#define NT 256
#define NWG 1024
#define PSC 256.0f                // 8 fraction bits
#define INV_PSC (1.0f / 256.0f)
#define DEPIDX(c, l) ((((l) & 15) * 136) + ((c) * 17) + ((l) >> 4))
#define NDEP4 544                 // 2176 u32 words as uint4

__global__ __launch_bounds__(NT)
void bq_main(const float* __restrict__ Wt,
             const float* __restrict__ wmin_in,
             const float* __restrict__ wmax_in,
             float* __restrict__ dq_out,
             float* __restrict__ partials)
{
    __shared__ uint4 dep4[NDEP4];    // packed {lo: dn@l, hi: up@l+1}
    __shared__ float wred[4];
    unsigned* dep = reinterpret_cast<unsigned*>(&dep4[0]);

    const int tid = threadIdx.x;
    const int wg  = blockIdx.x;
    const int n = wg >> 4, slab = wg & 15;   // block 0..63, 8-col slab 0..15

    // ---- prefetch: issue global loads first, hide zero-init under them
    const int row = tid >> 1;              // 0..127
    const int c0  = (tid & 1) * 4;         // 0,4
    const int R = (n >> 3) * 128 + row;
    const int C = (n & 7) * 128 + slab * 8 + c0;
    const float4 x4 = *reinterpret_cast<const float4*>(Wt + (size_t)R * 1024 + C);
    const float bmn = wmin_in[n], bmx = wmax_in[n];

    const float LN2 = 0.69314718055994531f;
    const float L2R = -(100.0f / 255.0f) * 1.4426950408889634f;  // log2(r)
    const float r = __builtin_amdgcn_exp2f(L2R);
    const float inv1mr  = 1.0f / (1.0f - r);
    const float inv1mr2 = inv1mr * inv1mr;
    const float Binf    = r * inv1mr2;

    // ---- zero dep with b128 stores
    {
        const uint4 z = make_uint4(0u, 0u, 0u, 0u);
        #pragma unroll
        for (int q = tid; q < NDEP4; q += NT) dep4[q] = z;
    }

    const float wmn = fminf(bmn, bmx - 1e-6f);
    const float wmx = fmaxf(bmx, wmn + 1e-6f);
    const float scale = wmx - wmn;
    const float invsc = 255.0f / (scale + 1e-6f);
    const float sc255 = scale * (1.0f / 255.0f);

    __syncthreads();

    // ---- phase 1: closed-form softmax + dequant + 1 packed deposit/element
    {
        float xs[4] = {x4.x, x4.y, x4.z, x4.w};
        float dq[4];
        #pragma unroll
        for (int u = 0; u < 4; ++u) {
            const float p = (xs[u] - wmn) * invsc;   // in [0,255)
            int ki = (int)p; ki = (ki > 254) ? 254 : ki;
            const float k   = (float)ki;
            const float f   = p - k;
            const float rf  = __builtin_amdgcn_exp2f(L2R * f);          // r^f
            const float r1f = __builtin_amdgcn_exp2f(L2R * (1.0f - f)); // r^{1-f}
            float Ak, yK, Aj, yJ;
            if (__builtin_expect(ki < 32 || ki > 223, 0)) {
                const float rk1 = __builtin_amdgcn_exp2f(L2R * (k + 1.0f));
                const float rj1 = __builtin_amdgcn_exp2f(L2R * (255.0f - k));
                Ak = (1.0f - rk1) * inv1mr;
                yK = k * Ak - (r - rk1 * ((k + 1.0f) - k * r)) * inv1mr2;
                Aj = (1.0f - rj1) * inv1mr;
                yJ = (k + 1.0f) * Aj
                   + (r - rj1 * ((255.0f - k) - (254.0f - k) * r)) * inv1mr2;
            } else {
                Ak = inv1mr; Aj = inv1mr;
                yK = k * inv1mr - Binf;
                yJ = (k + 1.0f) * inv1mr + Binf;
            }
            const float S  = rf * Ak + r1f * Aj;
            const float Wn = rf * yK + r1f * yJ;
            const float invS = __builtin_amdgcn_rcpf(S);
            dq[u] = Wn * invS * sc255 + wmn;
            const unsigned dn = (unsigned)(rf  * invS * PSC + 0.5f);
            const unsigned up = (unsigned)(r1f * invS * PSC + 0.5f);
            atomicAdd(&dep[DEPIDX(c0 + u, ki)], dn | (up << 16));
        }
        float4 o4; o4.x = dq[0]; o4.y = dq[1]; o4.z = dq[2]; o4.w = dq[3];
        *reinterpret_cast<float4*>(dq_out + (size_t)R * 1024 + C) = o4;
    }
    __syncthreads();

    // ---- fused phases 2+3: thread = (col 0..7, chunk 0..31), 8 levels each.
    // D[l] = sum_{k>=l} dn_k r^(k-l)   (lo halves, hi->lo)
    // U[l] = sum_{j<=l} up_j r^(l-j)   (hi half of word j-1 is up@j, lo->hi)
    float hsum = 0.0f;
    {
        const int col = tid >> 5;
        const int ch  = tid & 31;
        const int l0  = ch * 8;
        unsigned wd[9];
        wd[0] = (ch > 0) ? dep[DEPIDX(col, l0 - 1)] : 0u;
        #pragma unroll
        for (int j = 0; j < 8; ++j) wd[j + 1] = dep[DEPIDX(col, l0 + j)];

        float lvD[8], lvU[8];
        float vD = 0.0f;
        #pragma unroll
        for (int i = 7; i >= 0; --i) {
            vD = vD * r + (float)(wd[i + 1] & 0xffffu) * INV_PSC;
            lvD[i] = vD;
        }
        float vU = 0.0f;
        #pragma unroll
        for (int i = 0; i < 8; ++i) {
            vU = vU * r + (float)(wd[i] >> 16) * INV_PSC;
            lvU[i] = vU;
        }
        // cross-chunk carries, both directions in one pass
        float r8 = r * r; r8 = r8 * r8; r8 = r8 * r8;   // r^8
        float uD = vD, uU = vU, rp = r8;
        #pragma unroll
        for (int s = 1; s <= 16; s <<= 1) {
            const float oD = __shfl_down(uD, s, 32);
            const float oU = __shfl_up(uU, s, 32);
            if (ch + s < 32) uD += rp * oD;
            if (ch >= s)     uU += rp * oU;
            rp *= rp;
        }
        const float cvD = (ch < 31) ? __shfl_down(uD, 1, 32) : 0.0f;  // D[l0+8]
        const float cvU = (ch > 0)  ? __shfl_up(uU, 1, 32)  : 0.0f;   // U[l0-1]

        float DD[8];
        float m = cvD * r;
        #pragma unroll
        for (int i = 7; i >= 0; --i) { DD[i] = lvD[i] + m; m *= r; }
        m = cvU * r;
        #pragma unroll
        for (int i = 0; i < 8; ++i) {
            const float b  = DD[i] + lvU[i] + m; m *= r;
            const float ph = b * (1.0f / 16384.0f);
            hsum -= ph * (__builtin_amdgcn_logf(ph + 1e-6f) * LN2);
        }
    }
    #pragma unroll
    for (int off = 32; off > 0; off >>= 1) hsum += __shfl_down(hsum, off);
    if ((tid & 63) == 0) wred[tid >> 6] = hsum;
    __syncthreads();
    if (tid == 0) partials[wg] = wred[0] + wred[1] + wred[2] + wred[3];
}

__global__ __launch_bounds__(256)
void bq_finish(const float* __restrict__ partials, float* __restrict__ ent_out)
{
    const int tid = threadIdx.x;
    float v = partials[tid] + partials[tid + 256]
            + partials[tid + 512] + partials[tid + 768];
    #pragma unroll
    for (int off = 32; off > 0; off >>= 1) v += __shfl_down(v, off);
    __shared__ float buf[4];
    if ((tid & 63) == 0) buf[tid >> 6] = v;
    __syncthreads();
    if (tid == 0) ent_out[0] = buf[0] + buf[1] + buf[2] + buf[3];
}

extern "C" void kernel_launch(void* const* d_in, const int* in_sizes, int n_in,
                              void* d_out, int out_size, void* d_ws, size_t ws_size,
                              hipStream_t stream)
{
    const float* Wt  = (const float*)d_in[0];
    const float* wmn = (const float*)d_in[1];
    const float* wmx = (const float*)d_in[2];
    float* out = (float*)d_out;      // [1048576 dequant] + [1 entropy]
    float* partials = (float*)d_ws;  // 1024 floats

    bq_main<<<NWG, NT, 0, stream>>>(Wt, wmn, wmx, out, partials);
    bq_finish<<<1, 256, 0, stream>>>(partials, out + 1048576);
}

// Round 10
// 11.857 us; speedup vs baseline: 1.1069x; 1.1069x over previous
//
#include <hip/hip_runtime.h>
#include <math.h>

// BlockwiseQuantizationOptim: 1024x1024 f32, 64 blocks of 128x128, L=256, T=100.
// Closed-form softmax over uniform levels: e_l = r^|p-l|, r = exp(-100/255).
//   S  = rf*Ak + r1f*Aj
//   W  = rf*yK + r1f*yJ,  yK = k*Ak-Bk, yJ = (k+1)*Aj+Bj
// R10 = R8 base (512 WG x 512 thr — R9's 1024x256 reshape regressed) plus the
// ISOLATED interior fast path: for 32 <= k <= 223 (>99% of normal-block data)
// r^(k+1), r^(255-k) < 4e-6 underflow the closed forms to
//   Ak=Aj=1/(1-r), yK=k/(1-r)-Binf, yJ=(k+1)/(1-r)+Binf   (no exp2, ~10 fewer VALU)
// Edge lanes take the exact 2-exp2 formula (absmax-verified R8/R9).
// bin_mass: ONE ds_add_u32 per element packing down-seed (level k, bits 0..15)
// and up-seed (level k+1, bits 16..31) as 8.8 fixed point (half-sums < 2^16;
// u32 is the only native-fast LDS atomic — R2/R4 evidence).
// Phases 2+3 fused in-register: per (col, 8-level chunk) both geometric scans
// from 9 packed reads + two width-32 shfl carry scans, entropy in-register.
// Two-kernel finish — no device-scope fences/atomics in the hot kernel
// (R4/R5 regression: agent-scope release forces XCD-L2 writeback per WG).
//
// dep LDS layout: idx(c,l) = (l&15)*272 + c*17 + (l>>4)

#define NT 512
#define PSC 256.0f                // 8 fraction bits
#define INV_PSC (1.0f / 256.0f)
#define DEPIDX(c, l) ((((l) & 15) * 272) + ((c) * 17) + ((l) >> 4))
#define NDEP4 1088                // 4352 u32 words as uint4

__global__ __launch_bounds__(NT)
void bq_main(const float* __restrict__ Wt,
             const float* __restrict__ wmin_in,
             const float* __restrict__ wmax_in,
             float* __restrict__ dq_out,
             float* __restrict__ partials)
{
    __shared__ uint4 dep4[NDEP4];    // packed {lo: dn@l, hi: up@l+1}
    __shared__ float wred[8];
    unsigned* dep = reinterpret_cast<unsigned*>(&dep4[0]);

    const int tid = threadIdx.x;
    const int wg  = blockIdx.x;
    const int n = wg >> 3, slab = wg & 7;   // block 0..63, 16-col slab 0..7

    // ---- prefetch: issue global loads first, hide zero-init under them
    const int row = tid >> 2;              // 0..127
    const int c0  = (tid & 3) * 4;         // 0,4,8,12
    const int R = (n >> 3) * 128 + row;
    const int C = (n & 7) * 128 + slab * 16 + c0;
    const float4 x4 = *reinterpret_cast<const float4*>(Wt + (size_t)R * 1024 + C);
    const float bmn = wmin_in[n], bmx = wmax_in[n];

    const float LN2 = 0.69314718055994531f;
    const float L2R = -(100.0f / 255.0f) * 1.4426950408889634f;  // log2(r)
    const float r = __builtin_amdgcn_exp2f(L2R);
    const float inv1mr  = 1.0f / (1.0f - r);
    const float inv1mr2 = inv1mr * inv1mr;
    const float Binf    = r * inv1mr2;

    // ---- zero dep with b128 stores
    {
        const uint4 z = make_uint4(0u, 0u, 0u, 0u);
        #pragma unroll
        for (int q = tid; q < NDEP4; q += NT) dep4[q] = z;
    }

    const float wmn = fminf(bmn, bmx - 1e-6f);
    const float wmx = fmaxf(bmx, wmn + 1e-6f);
    const float scale = wmx - wmn;
    const float invsc = 255.0f / (scale + 1e-6f);
    const float sc255 = scale * (1.0f / 255.0f);

    __syncthreads();

    // ---- phase 1: closed-form softmax + dequant + 1 packed deposit/element
    {
        float xs[4] = {x4.x, x4.y, x4.z, x4.w};
        float dq[4];
        #pragma unroll
        for (int u = 0; u < 4; ++u) {
            const float p = (xs[u] - wmn) * invsc;   // in [0,255)
            int ki = (int)p; ki = (ki > 254) ? 254 : ki;
            const float k   = (float)ki;
            const float f   = p - k;
            const float rf  = __builtin_amdgcn_exp2f(L2R * f);          // r^f
            const float r1f = __builtin_amdgcn_exp2f(L2R * (1.0f - f)); // r^{1-f}
            float Ak, yK, Aj, yJ;
            if (__builtin_expect(ki < 32 || ki > 223, 0)) {
                const float rk1 = __builtin_amdgcn_exp2f(L2R * (k + 1.0f));
                const float rj1 = __builtin_amdgcn_exp2f(L2R * (255.0f - k));
                Ak = (1.0f - rk1) * inv1mr;
                yK = k * Ak - (r - rk1 * ((k + 1.0f) - k * r)) * inv1mr2;
                Aj = (1.0f - rj1) * inv1mr;
                yJ = (k + 1.0f) * Aj
                   + (r - rj1 * ((255.0f - k) - (254.0f - k) * r)) * inv1mr2;
            } else {
                Ak = inv1mr; Aj = inv1mr;
                yK = k * inv1mr - Binf;
                yJ = (k + 1.0f) * inv1mr + Binf;
            }
            const float S  = rf * Ak + r1f * Aj;
            const float Wn = rf * yK + r1f * yJ;
            const float invS = __builtin_amdgcn_rcpf(S);
            dq[u] = Wn * invS * sc255 + wmn;
            const unsigned dn = (unsigned)(rf  * invS * PSC + 0.5f);
            const unsigned up = (unsigned)(r1f * invS * PSC + 0.5f);
            atomicAdd(&dep[DEPIDX(c0 + u, ki)], dn | (up << 16));
        }
        float4 o4; o4.x = dq[0]; o4.y = dq[1]; o4.z = dq[2]; o4.w = dq[3];
        *reinterpret_cast<float4*>(dq_out + (size_t)R * 1024 + C) = o4;
    }
    __syncthreads();

    // ---- fused phases 2+3: thread = (col 0..15, chunk 0..31), 8 levels each.
    // D[l] = sum_{k>=l} dn_k r^(k-l)   (lo halves, hi->lo)
    // U[l] = sum_{j<=l} up_j r^(l-j)   (hi half of word j-1 is up@j, lo->hi)
    float hsum = 0.0f;
    {
        const int col = tid >> 5;
        const int ch  = tid & 31;
        const int l0  = ch * 8;
        unsigned wd[9];
        wd[0] = (ch > 0) ? dep[DEPIDX(col, l0 - 1)] : 0u;
        #pragma unroll
        for (int j = 0; j < 8; ++j) wd[j + 1] = dep[DEPIDX(col, l0 + j)];

        float lvD[8], lvU[8];
        float vD = 0.0f;
        #pragma unroll
        for (int i = 7; i >= 0; --i) {
            vD = vD * r + (float)(wd[i + 1] & 0xffffu) * INV_PSC;
            lvD[i] = vD;
        }
        float vU = 0.0f;
        #pragma unroll
        for (int i = 0; i < 8; ++i) {
            vU = vU * r + (float)(wd[i] >> 16) * INV_PSC;
            lvU[i] = vU;
        }
        // cross-chunk carries, both directions in one pass
        float r8 = r * r; r8 = r8 * r8; r8 = r8 * r8;   // r^8
        float uD = vD, uU = vU, rp = r8;
        #pragma unroll
        for (int s = 1; s <= 16; s <<= 1) {
            const float oD = __shfl_down(uD, s, 32);
            const float oU = __shfl_up(uU, s, 32);
            if (ch + s < 32) uD += rp * oD;
            if (ch >= s)     uU += rp * oU;
            rp *= rp;
        }
        const float cvD = (ch < 31) ? __shfl_down(uD, 1, 32) : 0.0f;  // D[l0+8]
        const float cvU = (ch > 0)  ? __shfl_up(uU, 1, 32)  : 0.0f;   // U[l0-1]

        float DD[8];
        float m = cvD * r;
        #pragma unroll
        for (int i = 7; i >= 0; --i) { DD[i] = lvD[i] + m; m *= r; }
        m = cvU * r;
        #pragma unroll
        for (int i = 0; i < 8; ++i) {
            const float b  = DD[i] + lvU[i] + m; m *= r;
            const float ph = b * (1.0f / 16384.0f);
            hsum -= ph * (__builtin_amdgcn_logf(ph + 1e-6f) * LN2);
        }
    }
    #pragma unroll
    for (int off = 32; off > 0; off >>= 1) hsum += __shfl_down(hsum, off);
    if ((tid & 63) == 0) wred[tid >> 6] = hsum;
    __syncthreads();
    if (tid == 0) {
        float tot = 0.0f;
        #pragma unroll
        for (int w = 0; w < 8; ++w) tot += wred[w];
        partials[wg] = tot;
    }
}

__global__ __launch_bounds__(256)
void bq_finish(const float* __restrict__ partials, float* __restrict__ ent_out)
{
    const int tid = threadIdx.x;
    float v = partials[tid] + partials[tid + 256];
    #pragma unroll
    for (int off = 32; off > 0; off >>= 1) v += __shfl_down(v, off);
    __shared__ float buf[4];
    if ((tid & 63) == 0) buf[tid >> 6] = v;
    __syncthreads();
    if (tid == 0) ent_out[0] = buf[0] + buf[1] + buf[2] + buf[3];
}

extern "C" void kernel_launch(void* const* d_in, const int* in_sizes, int n_in,
                              void* d_out, int out_size, void* d_ws, size_t ws_size,
                              hipStream_t stream)
{
    const float* Wt  = (const float*)d_in[0];
    const float* wmn = (const float*)d_in[1];
    const float* wmx = (const float*)d_in[2];
    float* out = (float*)d_out;      // [1048576 dequant] + [1 entropy]
    float* partials = (float*)d_ws;  // 512 floats

    bq_main<<<512, NT, 0, stream>>>(Wt, wmn, wmx, out, partials);
    bq_finish<<<1, 256, 0, stream>>>(partials, out + 1048576);
}